// Round 7
// baseline (251.159 us; speedup 1.0000x reference)
//
#include <hip/hip_runtime.h>
#include <math.h>

// RG-LRU: B=4, T=4096, W=1024, H=8, BW=128
// Single-pass chained scan, CHUNK=64, 2048 blocks (R5 structure) + VALU diet (R6 inner
// loops) + __launch_bounds__(512,8) pinning the 64-VGPR / 8-waves-per-SIMD tier.
#define NB 4
#define NT 4096
#define NW 1024
#define NH 8
#define CHUNK 64
#define NCH 64          // NT / CHUNK
#define STRIDE_A 136    // bf16 elems per LDS A-row: 272 B = 17*16 (16B-aligned, bank-friendly)
#define LOG2E 1.4426950408889634f

typedef __attribute__((ext_vector_type(8))) short short8;
typedef __attribute__((ext_vector_type(4))) float f32x4;
typedef unsigned long long u64;

__device__ __forceinline__ short bf16rne(float f) {
    unsigned u = __float_as_uint(f);
    u += 0x7fffu + ((u >> 16) & 1u);      // round-to-nearest-even
    return (short)(u >> 16);
}

// pack two fp32 -> two bf16 (RNE), one instruction
__device__ __forceinline__ unsigned cvtpk(float lo, float hi) {
    unsigned r;
    asm("v_cvt_pk_bf16_f32 %0, %1, %2" : "=v"(r) : "v"(lo), "v"(hi));
    return r;
}

// ---------------- K0: convert w_in/w_a to frag-major bf16 + NaN-poison AGH ----------
// wfH dst: ((((h*2+g)*4+ks)*8 + ntg)*64 + lane)*8 + jj
// Poisons AGH (2 MiB = 131072 uint4) with NaN: packed (A,H) aggregates are
// self-validating per 64-bit word (atomic 8B store/load; NaN A => unpublished).
__global__ __launch_bounds__(256)
void k0_wfrag(const float* __restrict__ w_in, const float* __restrict__ w_a,
              short* __restrict__ wfH, uint4* __restrict__ poison)
{
    int idx = blockIdx.x * 256 + threadIdx.x;   // over 2*8*128*32 = 65536
    uint4 nv; nv.x = nv.y = nv.z = nv.w = 0xFFFFFFFFu;   // NaN
    poison[idx]         = nv;
    poison[idx + 65536] = nv;

    int j4 = (idx & 31) * 4;
    int i  = (idx >> 5) & 127;
    int h  = (idx >> 12) & 7;
    int g  = idx >> 15;
    const float* w = g ? w_a : w_in;
    float4 v = *(const float4*)&w[((size_t)h * 128 + i) * 128 + j4];
    const float vf[4] = {v.x, v.y, v.z, v.w};
    const int ks = i >> 5, q = (i >> 3) & 3, jj = i & 7;
    #pragma unroll
    for (int d = 0; d < 4; ++d) {
        int j = j4 + d;
        int lane = q * 16 + (j & 15);
        int ntg = j >> 4;
        size_t dst = ((size_t)(((h * 2 + g) * 4 + ks) * 8 + ntg) * 64 + lane) * 8 + jj;
        wfH[dst] = bf16rne(vf[d]);
    }
}

// ---------------- K: MFMA gates + chunk scan + full-wave look-back + store ----------
// grid (NH, NB*NCH=256), block 512 (8 waves); block tile = 64 t x 128 w (one head).
// Grid linear order monotone in c per (h,b) chain -> with in-order dispatch every
// resident block's predecessors are resident-or-retired (no deadlock at any residency).
// AGH[chain][chunk][col] = packed (float A, float H): h_out = A*h_in + H. NaN = unpublished.
// EVERY chunk publishes its aggregate right after compute (before its own look-back),
// so aggregates appear at compute-finish time with zero serial chaining.
__global__ __launch_bounds__(512, 8)
void k_fused(const float* __restrict__ x, const int* __restrict__ seg,
             const float* __restrict__ a_param,
             const float* __restrict__ b_in, const float* __restrict__ b_a,
             const short* __restrict__ wfH,
             float2* __restrict__ AGH, float* __restrict__ out)
{
    __shared__ short sA[CHUNK * STRIDE_A];   // 17.4 KB
    __shared__ float sMask[CHUNK];           // 256 B (reset mask, broadcast reads)

    const int h   = blockIdx.x;
    const int bc  = blockIdx.y;           // b*NCH + c
    const int b   = bc >> 6, c = bc & 63;
    const int tid = threadIdx.x;
    const int wave = tid >> 6, lane = tid & 63;   // wave = n-tile group (0..7)
    const int quad = lane >> 4, m = lane & 15;
    const int row0 = b * NT + c * CHUNK;          // global row into [B*T]

    // ---- stage A: x tile (64 t x 128 k) -> bf16 LDS via v_cvt_pk_bf16_f32 ----
    {
        const int r  = tid >> 3;           // 0..63
        const int k0 = (tid & 7) * 16;     // 0,16,..,112
        const float4* px = (const float4*)(x + (size_t)(row0 + r) * NW + h * 128 + k0);
        float4 v0 = px[0], v1 = px[1], v2 = px[2], v3 = px[3];
        uint4 u0, u1;
        u0.x = cvtpk(v0.x, v0.y); u0.y = cvtpk(v0.z, v0.w);
        u0.z = cvtpk(v1.x, v1.y); u0.w = cvtpk(v1.z, v1.w);
        u1.x = cvtpk(v2.x, v2.y); u1.y = cvtpk(v2.z, v2.w);
        u1.z = cvtpk(v3.x, v3.y); u1.w = cvtpk(v3.z, v3.w);
        *(uint4*)&sA[r * STRIDE_A + k0]     = u0;
        *(uint4*)&sA[r * STRIDE_A + k0 + 8] = u1;
        if ((tid & 7) == 0) sMask[r] = (seg[row0 + r] == 0) ? 0.f : 1.f;
    }
    __syncthreads();

    // ---- MFMA main loop over K (A from LDS, B frags from L2-resident wfH) ----
    f32x4 acc[2][4];  // [gate][mt]
    #pragma unroll
    for (int g = 0; g < 2; ++g)
        #pragma unroll
        for (int mt = 0; mt < 4; ++mt)
            acc[g][mt] = (f32x4){0.f, 0.f, 0.f, 0.f};

    #pragma unroll
    for (int ks = 0; ks < 4; ++ks) {
        short8 ah[4];
        #pragma unroll
        for (int mt = 0; mt < 4; ++mt)
            ah[mt] = *(const short8*)&sA[(mt * 16 + m) * STRIDE_A + ks * 32 + quad * 8];
        #pragma unroll
        for (int g = 0; g < 2; ++g) {
            const size_t fo = ((size_t)(((h * 2 + g) * 4 + ks) * 8 + wave) * 64 + lane) * 8;
            short8 bh = *(const short8*)(wfH + fo);
            #pragma unroll
            for (int mt = 0; mt < 4; ++mt)
                acc[g][mt] = __builtin_amdgcn_mfma_f32_16x16x32_bf16(ah[mt], bh, acc[g][mt], 0, 0, 0);
        }
    }

    // ---- per-column parameters ----
    const int col  = wave * 16 + m;       // 0..127 within head
    const int colg = h * 128 + col;
    const float bi2 = -LOG2E * b_in[colg];                          // exp(-(acc+bi)) = exp2(fma(acc,-L,bi2))
    const float ba2 = -LOG2E * b_a[colg];
    const float c2l = -8.0f * LOG2E * log1pf(expf(a_param[colg]));  // a = exp2(c2l*ga)

    // ---- epilogue + chunk-local scan (C layout: row = quad*4+reg, col = lane&15) ----
    float cA = 1.f, cH = 0.f;             // carry across m-tiles (per column)
    float Pf[4][4], Hf[4][4];             // retained: out = Hf + Pf * h_prev
    #pragma unroll
    for (int mt = 0; mt < 4; ++mt) {
        float lP[4], lH[4];
        {
            float xv[4];
            #pragma unroll
            for (int r = 0; r < 4; ++r) {
                const int rowi = row0 + mt * 16 + quad * 4 + r;
                xv[r] = x[(size_t)rowi * NW + colg];
            }
            const float4 mk4 = *(const float4*)&sMask[mt * 16 + quad * 4];
            const float mk[4] = {mk4.x, mk4.y, mk4.z, mk4.w};
            #pragma unroll
            for (int r = 0; r < 4; ++r) {
                const float ex = __builtin_amdgcn_exp2f(fmaf(acc[0][mt][r], -LOG2E, bi2));
                const float gx = __fdividef(1.f, 1.f + ex);
                const float ea = __builtin_amdgcn_exp2f(fmaf(acc[1][mt][r], -LOG2E, ba2));
                const float ga = __fdividef(1.f, 1.f + ea);
                const float a  = __builtin_amdgcn_exp2f(c2l * ga);
                // a < 1 strictly (c2l<0, ga>0) => fma(-a,a,1) >= 0 exactly
                const float mult = __builtin_amdgcn_sqrtf(fmaf(-a, a, 1.f));
                const float av = a * mk[r];
                const float nx = xv[r] * gx * mult;
                lP[r] = (r == 0) ? av : lP[r - 1] * av;
                lH[r] = (r == 0) ? nx : fmaf(av, lH[r - 1], nx);
            }
        }
        // cross-quad inclusive scan of quad totals
        float iA = lP[3], iH = lH[3];
        float uA = __shfl_up(iA, 16), uH = __shfl_up(iH, 16);
        if (quad >= 1) { iH = fmaf(iA, uH, iH); iA = uA * iA; }
        uA = __shfl_up(iA, 32); uH = __shfl_up(iH, 32);
        if (quad >= 2) { iH = fmaf(iA, uH, iH); iA = uA * iA; }
        // exclusive prefix for this quad
        float eA = __shfl_up(iA, 16), eH = __shfl_up(iH, 16);
        if (quad == 0) { eA = 1.f; eH = 0.f; }
        // 16-t tile total (quad 3 inclusive), broadcast per column
        const float mAt = __shfl(iA, 48 + m);
        const float mHt = __shfl(iH, 48 + m);
        // prefix = carry ∘ quad-exclusive; update carry
        const float pA = cA * eA;
        const float pH = fmaf(eA, cH, eH);
        cH = fmaf(mAt, cH, mHt);
        cA = cA * mAt;
        #pragma unroll
        for (int r = 0; r < 4; ++r) {
            Pf[mt][r] = pA * lP[r];
            Hf[mt][r] = fmaf(lP[r], pH, lH[r]);
        }
    }
    // NOTE: cA,cH (chunk totals) are replicated across quads for each (wave,m).

    // ---- publish packed aggregate FIRST (zero serial chaining between blocks) ----
    const size_t cb0 = (size_t)(h * NB + b) * NCH * 128;   // chain base (float2 units)
    if (quad == 0) {
        const u64 pk = ((u64)__float_as_uint(cH) << 32) | (u64)__float_as_uint(cA);
        __hip_atomic_store((u64*)&AGH[cb0 + (size_t)c * 128 + col], pk,
                           __ATOMIC_RELAXED, __HIP_MEMORY_SCOPE_AGENT);
    }

    // ---- full-wave look-back: windows of 16 predecessors, 1 round trip each ----
    // Window w: lane (quad q, m) owns preds {c-1-16w-4q-j, j=0..3} of column m's chain,
    // folds them near->far in registers (retry on unpublished), then ordered 4-step
    // shfl composition; windows compose via running (accA, hp). All lanes get h_prev.
    float hp = 0.f;
    {
        float accA = 1.f;
        const int nw = (c + 15) >> 4;       // windows needed (0 for c==0)
        for (int w = 0; w < nw; ++w) {
            const int base = c - 1 - (w * 16 + quad * 4);
            const int nj   = base < 0 ? 0 : (base >= 3 ? 4 : base + 1);
            float a_ = 1.f, h_ = 0.f;
            if (nj > 0) {
                int folded = 0;
                for (;;) {
                    u64 pk[4];
                    #pragma unroll
                    for (int j = 0; j < 4; ++j) {
                        int idx = base - j; idx = idx < 0 ? 0 : idx;
                        pk[j] = __hip_atomic_load((const u64*)&AGH[cb0 + (size_t)idx * 128 + col],
                                                  __ATOMIC_RELAXED, __HIP_MEMORY_SCOPE_AGENT);
                    }
                    bool stall = false;
                    #pragma unroll
                    for (int j = 0; j < 4; ++j) {
                        if (j < folded || j >= nj || stall) continue;
                        const float A_ = __uint_as_float((unsigned)pk[j]);
                        if (__builtin_isnan(A_)) { stall = true; continue; }
                        const float H_ = __uint_as_float((unsigned)(pk[j] >> 32));
                        h_ = fmaf(a_, H_, h_);      // fold aggregate near->far
                        a_ *= A_;
                        folded = j + 1;
                    }
                    if (folded >= nj) break;
                    __builtin_amdgcn_s_sleep(4);
                }
            }
            // ordered cross-quad composition (q=0 nearest)
            #pragma unroll
            for (int q = 0; q < 4; ++q) {
                const float Aq = __shfl(a_, q * 16 + m);
                const float Hq = __shfl(h_, q * 16 + m);
                hp = fmaf(accA, Hq, hp);
                accA *= Aq;
            }
        }
    }

    // ---- final stores: out = Hf + Pf * h_prev (64B sectors per quad-row) ----
    #pragma unroll
    for (int mt = 0; mt < 4; ++mt) {
        #pragma unroll
        for (int r = 0; r < 4; ++r) {
            const int rowi = row0 + mt * 16 + quad * 4 + r;
            out[(size_t)rowi * NW + colg] = fmaf(Pf[mt][r], hp, Hf[mt][r]);
        }
    }
}

extern "C" void kernel_launch(void* const* d_in, const int* in_sizes, int n_in,
                              void* d_out, int out_size, void* d_ws, size_t ws_size,
                              hipStream_t stream)
{
    (void)in_sizes; (void)n_in; (void)out_size; (void)ws_size;
    const float* x    = (const float*)d_in[0];
    const int*   seg  = (const int*)  d_in[1];
    const float* ap   = (const float*)d_in[2];
    const float* w_in = (const float*)d_in[3];
    const float* b_in = (const float*)d_in[4];
    const float* w_a  = (const float*)d_in[5];
    const float* b_a  = (const float*)d_in[6];
    float* out = (float*)d_out;

    // ws layout (~2.5 MiB): AGH (2 MiB packed aggregates, NaN-poisoned by k0) + wfH (0.5 MiB)
    const size_t NTOP = (size_t)NH * NB * NCH * 128;   // 262144 float2
    float2* AGH = (float2*)d_ws;
    short*  wfH = (short*)(AGH + NTOP);

    k0_wfrag<<<256, 256, 0, stream>>>(w_in, w_a, wfH, (uint4*)AGH);
    dim3 g1(NH, NB * NCH);
    k_fused<<<g1, 512, 0, stream>>>(x, seg, ap, b_in, b_a, wfH, AGH, out);
}

// Round 8
// 161.333 us; speedup vs baseline: 1.5568x; 1.5568x over previous
//
#include <hip/hip_runtime.h>
#include <math.h>

// RG-LRU: B=4, T=4096, W=1024, H=8, BW=128
// Single-pass chained scan, CHUNK=64, 2048 blocks (R5 structure, VGPR~60 no-spill tier)
// + VALU diet (cvt_pk staging, exp2-folded epilogue). NO waves-per-EU forcing:
// unified VGPR/AGPR file means acc[2][4] (32 AGPRs) counts against the budget, so the
// 8-waves/SIMD (<=64 total) tier is unreachable -- natural ~92 total = 5 waves/SIMD.
#define NB 4
#define NT 4096
#define NW 1024
#define NH 8
#define CHUNK 64
#define NCH 64          // NT / CHUNK
#define STRIDE_A 136    // bf16 elems per LDS A-row: 272 B = 17*16 (16B-aligned, bank-friendly)
#define LOG2E 1.4426950408889634f

typedef __attribute__((ext_vector_type(8))) short short8;
typedef __attribute__((ext_vector_type(4))) float f32x4;
typedef unsigned long long u64;

__device__ __forceinline__ short bf16rne(float f) {
    unsigned u = __float_as_uint(f);
    u += 0x7fffu + ((u >> 16) & 1u);      // round-to-nearest-even
    return (short)(u >> 16);
}

// pack two fp32 -> two bf16 (RNE), one instruction
__device__ __forceinline__ unsigned cvtpk(float lo, float hi) {
    unsigned r;
    asm("v_cvt_pk_bf16_f32 %0, %1, %2" : "=v"(r) : "v"(lo), "v"(hi));
    return r;
}

// ---------------- K0: convert w_in/w_a to frag-major bf16 + NaN-poison AGH ----------
// wfH dst: ((((h*2+g)*4+ks)*8 + ntg)*64 + lane)*8 + jj
// Poisons AGH (2 MiB = 131072 uint4) with NaN: packed (A,H) aggregates are
// self-validating per 64-bit word (atomic 8B store/load; NaN A => unpublished).
__global__ __launch_bounds__(256)
void k0_wfrag(const float* __restrict__ w_in, const float* __restrict__ w_a,
              short* __restrict__ wfH, uint4* __restrict__ poison)
{
    int idx = blockIdx.x * 256 + threadIdx.x;   // over 2*8*128*32 = 65536
    uint4 nv; nv.x = nv.y = nv.z = nv.w = 0xFFFFFFFFu;   // NaN
    poison[idx]         = nv;
    poison[idx + 65536] = nv;

    int j4 = (idx & 31) * 4;
    int i  = (idx >> 5) & 127;
    int h  = (idx >> 12) & 7;
    int g  = idx >> 15;
    const float* w = g ? w_a : w_in;
    float4 v = *(const float4*)&w[((size_t)h * 128 + i) * 128 + j4];
    const float vf[4] = {v.x, v.y, v.z, v.w};
    const int ks = i >> 5, q = (i >> 3) & 3, jj = i & 7;
    #pragma unroll
    for (int d = 0; d < 4; ++d) {
        int j = j4 + d;
        int lane = q * 16 + (j & 15);
        int ntg = j >> 4;
        size_t dst = ((size_t)(((h * 2 + g) * 4 + ks) * 8 + ntg) * 64 + lane) * 8 + jj;
        wfH[dst] = bf16rne(vf[d]);
    }
}

// ---------------- K: MFMA gates + chunk scan + full-wave look-back + store ----------
// grid (NH, NB*NCH=256), block 512 (8 waves); block tile = 64 t x 128 w (one head).
// Grid linear order monotone in c per (h,b) chain -> with in-order dispatch every
// resident block's predecessors are resident-or-retired (no deadlock at any residency).
// AGH[chain][chunk][col] = packed (float A, float H): h_out = A*h_in + H. NaN = unpublished.
// EVERY chunk publishes its aggregate right after compute (before its own look-back),
// so aggregates appear at compute-finish time with zero serial chaining.
__global__ __launch_bounds__(512)
void k_fused(const float* __restrict__ x, const int* __restrict__ seg,
             const float* __restrict__ a_param,
             const float* __restrict__ b_in, const float* __restrict__ b_a,
             const short* __restrict__ wfH,
             float2* __restrict__ AGH, float* __restrict__ out)
{
    __shared__ short sA[CHUNK * STRIDE_A];   // 17.4 KB
    __shared__ float sMask[CHUNK];           // 256 B (reset mask, broadcast reads)

    const int h   = blockIdx.x;
    const int bc  = blockIdx.y;           // b*NCH + c
    const int b   = bc >> 6, c = bc & 63;
    const int tid = threadIdx.x;
    const int wave = tid >> 6, lane = tid & 63;   // wave = n-tile group (0..7)
    const int quad = lane >> 4, m = lane & 15;
    const int row0 = b * NT + c * CHUNK;          // global row into [B*T]

    // ---- stage A: x tile (64 t x 128 k) -> bf16 LDS via v_cvt_pk_bf16_f32 ----
    {
        const int r  = tid >> 3;           // 0..63
        const int k0 = (tid & 7) * 16;     // 0,16,..,112
        const float4* px = (const float4*)(x + (size_t)(row0 + r) * NW + h * 128 + k0);
        float4 v0 = px[0], v1 = px[1], v2 = px[2], v3 = px[3];
        uint4 u0, u1;
        u0.x = cvtpk(v0.x, v0.y); u0.y = cvtpk(v0.z, v0.w);
        u0.z = cvtpk(v1.x, v1.y); u0.w = cvtpk(v1.z, v1.w);
        u1.x = cvtpk(v2.x, v2.y); u1.y = cvtpk(v2.z, v2.w);
        u1.z = cvtpk(v3.x, v3.y); u1.w = cvtpk(v3.z, v3.w);
        *(uint4*)&sA[r * STRIDE_A + k0]     = u0;
        *(uint4*)&sA[r * STRIDE_A + k0 + 8] = u1;
        if ((tid & 7) == 0) sMask[r] = (seg[row0 + r] == 0) ? 0.f : 1.f;
    }
    __syncthreads();

    // ---- MFMA main loop over K (A from LDS, B frags from L2-resident wfH) ----
    f32x4 acc[2][4];  // [gate][mt]
    #pragma unroll
    for (int g = 0; g < 2; ++g)
        #pragma unroll
        for (int mt = 0; mt < 4; ++mt)
            acc[g][mt] = (f32x4){0.f, 0.f, 0.f, 0.f};

    #pragma unroll
    for (int ks = 0; ks < 4; ++ks) {
        short8 ah[4];
        #pragma unroll
        for (int mt = 0; mt < 4; ++mt)
            ah[mt] = *(const short8*)&sA[(mt * 16 + m) * STRIDE_A + ks * 32 + quad * 8];
        #pragma unroll
        for (int g = 0; g < 2; ++g) {
            const size_t fo = ((size_t)(((h * 2 + g) * 4 + ks) * 8 + wave) * 64 + lane) * 8;
            short8 bh = *(const short8*)(wfH + fo);
            #pragma unroll
            for (int mt = 0; mt < 4; ++mt)
                acc[g][mt] = __builtin_amdgcn_mfma_f32_16x16x32_bf16(ah[mt], bh, acc[g][mt], 0, 0, 0);
        }
    }

    // ---- per-column parameters ----
    const int col  = wave * 16 + m;       // 0..127 within head
    const int colg = h * 128 + col;
    const float bi2 = -LOG2E * b_in[colg];                          // exp(-(acc+bi)) = exp2(fma(acc,-L,bi2))
    const float ba2 = -LOG2E * b_a[colg];
    const float c2l = -8.0f * LOG2E * log1pf(expf(a_param[colg]));  // a = exp2(c2l*ga)

    // ---- epilogue + chunk-local scan (C layout: row = quad*4+reg, col = lane&15) ----
    float cA = 1.f, cH = 0.f;             // carry across m-tiles (per column)
    float Pf[4][4], Hf[4][4];             // retained: out = Hf + Pf * h_prev
    #pragma unroll
    for (int mt = 0; mt < 4; ++mt) {
        float lP[4], lH[4];
        {
            float xv[4];
            #pragma unroll
            for (int r = 0; r < 4; ++r) {
                const int rowi = row0 + mt * 16 + quad * 4 + r;
                xv[r] = x[(size_t)rowi * NW + colg];
            }
            const float4 mk4 = *(const float4*)&sMask[mt * 16 + quad * 4];
            const float mk[4] = {mk4.x, mk4.y, mk4.z, mk4.w};
            #pragma unroll
            for (int r = 0; r < 4; ++r) {
                const float ex = __builtin_amdgcn_exp2f(fmaf(acc[0][mt][r], -LOG2E, bi2));
                const float gx = __fdividef(1.f, 1.f + ex);
                const float ea = __builtin_amdgcn_exp2f(fmaf(acc[1][mt][r], -LOG2E, ba2));
                const float ga = __fdividef(1.f, 1.f + ea);
                const float a  = __builtin_amdgcn_exp2f(c2l * ga);
                // a < 1 strictly (c2l<0, ga>0) => fma(-a,a,1) >= 0 exactly
                const float mult = __builtin_amdgcn_sqrtf(fmaf(-a, a, 1.f));
                const float av = a * mk[r];
                const float nx = xv[r] * gx * mult;
                lP[r] = (r == 0) ? av : lP[r - 1] * av;
                lH[r] = (r == 0) ? nx : fmaf(av, lH[r - 1], nx);
            }
        }
        // cross-quad inclusive scan of quad totals
        float iA = lP[3], iH = lH[3];
        float uA = __shfl_up(iA, 16), uH = __shfl_up(iH, 16);
        if (quad >= 1) { iH = fmaf(iA, uH, iH); iA = uA * iA; }
        uA = __shfl_up(iA, 32); uH = __shfl_up(iH, 32);
        if (quad >= 2) { iH = fmaf(iA, uH, iH); iA = uA * iA; }
        // exclusive prefix for this quad
        float eA = __shfl_up(iA, 16), eH = __shfl_up(iH, 16);
        if (quad == 0) { eA = 1.f; eH = 0.f; }
        // 16-t tile total (quad 3 inclusive), broadcast per column
        const float mAt = __shfl(iA, 48 + m);
        const float mHt = __shfl(iH, 48 + m);
        // prefix = carry ∘ quad-exclusive; update carry
        const float pA = cA * eA;
        const float pH = fmaf(eA, cH, eH);
        cH = fmaf(mAt, cH, mHt);
        cA = cA * mAt;
        #pragma unroll
        for (int r = 0; r < 4; ++r) {
            Pf[mt][r] = pA * lP[r];
            Hf[mt][r] = fmaf(lP[r], pH, lH[r]);
        }
    }
    // NOTE: cA,cH (chunk totals) are replicated across quads for each (wave,m).

    // ---- publish packed aggregate FIRST (zero serial chaining between blocks) ----
    const size_t cb0 = (size_t)(h * NB + b) * NCH * 128;   // chain base (float2 units)
    if (quad == 0) {
        const u64 pk = ((u64)__float_as_uint(cH) << 32) | (u64)__float_as_uint(cA);
        __hip_atomic_store((u64*)&AGH[cb0 + (size_t)c * 128 + col], pk,
                           __ATOMIC_RELAXED, __HIP_MEMORY_SCOPE_AGENT);
    }

    // ---- full-wave look-back: windows of 16 predecessors, 1 round trip each ----
    // Window w: lane (quad q, m) owns preds {c-1-16w-4q-j, j=0..3} of column m's chain,
    // folds them near->far in registers (retry on unpublished), then ordered 4-step
    // shfl composition; windows compose via running (accA, hp). All lanes get h_prev.
    float hp = 0.f;
    {
        float accA = 1.f;
        const int nw = (c + 15) >> 4;       // windows needed (0 for c==0)
        for (int w = 0; w < nw; ++w) {
            const int base = c - 1 - (w * 16 + quad * 4);
            const int nj   = base < 0 ? 0 : (base >= 3 ? 4 : base + 1);
            float a_ = 1.f, h_ = 0.f;
            if (nj > 0) {
                int folded = 0;
                for (;;) {
                    u64 pk[4];
                    #pragma unroll
                    for (int j = 0; j < 4; ++j) {
                        int idx = base - j; idx = idx < 0 ? 0 : idx;
                        pk[j] = __hip_atomic_load((const u64*)&AGH[cb0 + (size_t)idx * 128 + col],
                                                  __ATOMIC_RELAXED, __HIP_MEMORY_SCOPE_AGENT);
                    }
                    bool stall = false;
                    #pragma unroll
                    for (int j = 0; j < 4; ++j) {
                        if (j < folded || j >= nj || stall) continue;
                        const float A_ = __uint_as_float((unsigned)pk[j]);
                        if (__builtin_isnan(A_)) { stall = true; continue; }
                        const float H_ = __uint_as_float((unsigned)(pk[j] >> 32));
                        h_ = fmaf(a_, H_, h_);      // fold aggregate near->far
                        a_ *= A_;
                        folded = j + 1;
                    }
                    if (folded >= nj) break;
                    __builtin_amdgcn_s_sleep(4);
                }
            }
            // ordered cross-quad composition (q=0 nearest)
            #pragma unroll
            for (int q = 0; q < 4; ++q) {
                const float Aq = __shfl(a_, q * 16 + m);
                const float Hq = __shfl(h_, q * 16 + m);
                hp = fmaf(accA, Hq, hp);
                accA *= Aq;
            }
        }
    }

    // ---- final stores: out = Hf + Pf * h_prev (64B sectors per quad-row) ----
    #pragma unroll
    for (int mt = 0; mt < 4; ++mt) {
        #pragma unroll
        for (int r = 0; r < 4; ++r) {
            const int rowi = row0 + mt * 16 + quad * 4 + r;
            out[(size_t)rowi * NW + colg] = fmaf(Pf[mt][r], hp, Hf[mt][r]);
        }
    }
}

extern "C" void kernel_launch(void* const* d_in, const int* in_sizes, int n_in,
                              void* d_out, int out_size, void* d_ws, size_t ws_size,
                              hipStream_t stream)
{
    (void)in_sizes; (void)n_in; (void)out_size; (void)ws_size;
    const float* x    = (const float*)d_in[0];
    const int*   seg  = (const int*)  d_in[1];
    const float* ap   = (const float*)d_in[2];
    const float* w_in = (const float*)d_in[3];
    const float* b_in = (const float*)d_in[4];
    const float* w_a  = (const float*)d_in[5];
    const float* b_a  = (const float*)d_in[6];
    float* out = (float*)d_out;

    // ws layout (~2.5 MiB): AGH (2 MiB packed aggregates, NaN-poisoned by k0) + wfH (0.5 MiB)
    const size_t NTOP = (size_t)NH * NB * NCH * 128;   // 262144 float2
    float2* AGH = (float2*)d_ws;
    short*  wfH = (short*)(AGH + NTOP);

    k0_wfrag<<<256, 256, 0, stream>>>(w_in, w_a, wfH, (uint4*)AGH);
    dim3 g1(NH, NB * NCH);
    k_fused<<<g1, 512, 0, stream>>>(x, seg, ap, b_in, b_a, wfH, AGH, out);
}